// Round 12
// baseline (185.471 us; speedup 1.0000x reference)
//
#include <hip/hip_runtime.h>
#include <hip/hip_bf16.h>

// HarmonicFullyConnectedTensorProduct, lmax=2, MUL=64, B=1024, 11 paths.
// out[z,w,k] += sum_{u,v,m,n} x1[z,u,m] x2[z,v,n] W[p,w,u,v] C_p[m,n,k]
//
// Round 12: register-resident B-fragments; NO per-iteration barrier, NO sT.
//   MFMA B-frag lane (q,ln) needs T[z=ln][v=q*8+j] = sum_n x2[z,v,n]*c1[z,u,k,n]:
//   each lane holds its 8 x2 rows in regs (u-invariant) and its z's c1 row
//   (bf16 LDS slab, register-prefetched one u ahead) -> dot -> cvt_pk_bf16
//   -> MFMA, all in registers. 4 barriers/block total (2 slab builds).
//   Block = (path, ztile, usub x32u, vhalf x32v); wave = 16 z, ROWT w-tiles.
//   4 partial slices (usub,vh) -> reduce_out (unchanged, validated).

#define NTHREADS 256
#define SMEM_BYTES 34304

typedef __attribute__((ext_vector_type(4))) float f32x4;
typedef __attribute__((ext_vector_type(8))) short s16x8;

__device__ __forceinline__ unsigned short f2bf(float x) {
    union { float f; unsigned u; } v; v.f = x;
    unsigned r = v.u + 0x7fffu + ((v.u >> 16) & 1u);   // RNE
    return (unsigned short)(r >> 16);
}
__device__ __forceinline__ float bf2f(unsigned short h) {
    union { unsigned u; float f; } v; v.u = ((unsigned)h) << 16;
    return v.f;
}
__device__ __forceinline__ unsigned pk2bf(float a, float b) {
    union { __hip_bfloat162 h; unsigned u; } v;
    v.h = __float22bfloat162_rn(make_float2(a, b));    // v_cvt_pk_bf16_f32
    return v.u;
}

// ---------------- prep: W fp32 [p][w][u][v] -> bf16 [p][u][w][v] ----------------

__global__ __launch_bounds__(NTHREADS) void prep_w(const float* __restrict__ W,
                                                   unsigned short* __restrict__ Wb)
{
    int id = blockIdx.x * NTHREADS + threadIdx.x;   // (p,u,w,v4): 11*64*64*16
    int v4 = (id & 15) << 2;
    int w  = (id >> 4) & 63;
    int u  = (id >> 10) & 63;
    int p  = id >> 16;
    float4 f = *(const float4*)(W + (((size_t)p * 64 + w) * 64 + u) * 64 + v4);
    ushort4 h;
    h.x = f2bf(f.x); h.y = f2bf(f.y); h.z = f2bf(f.z); h.w = f2bf(f.w);
    *(ushort4*)(Wb + (((size_t)p * 64 + u) * 64 + w) * 64 + v4) = h;
}

// ---------------- main ----------------

struct KArgs {
    const float*          x1[3];
    const float*          x2[3];
    const unsigned short* Wb;
    const float*          C[11];
    float*                part[11];   // per-path partials [4 slice][1024][64][K1]
};

template <int M1, int N1, int K1, int ROWT, int KNP>
__device__ __forceinline__ void run_path(const float* __restrict__ x1g,
                                         const float* __restrict__ x2g,
                                         const unsigned short* __restrict__ Wbp,
                                         const float* __restrict__ Cg,
                                         float* __restrict__ partp,
                                         int local, char* __restrict__ smem)
{
    constexpr int KN   = K1 * N1;
    constexpr int NB   = KNP / 8;            // b128 c1 reads per (z,u)
    constexpr int ZG   = (ROWT == 2) ? 2 : 4;  // z-groups (waves per w-group)
    constexpr int ZT   = ZG * 16;            // z per block
    constexpr int ZSTR = 16 * KNP + 8;       // slab z-stride (bf16 elems; 4 dw mod 32)
    static_assert(KN <= KNP && KNP % 8 == 0, "");
    static_assert(512 + ZT * ZSTR * 2 <= SMEM_BYTES, "LDS");

    float*          sC  = (float*)smem;                   // [M1*N1*K1]
    unsigned short* sc1 = (unsigned short*)(smem + 512);  // [ZT][ZSTR] bf16

    const int t = threadIdx.x, lane = t & 63, wave = t >> 6;
    const int ln = lane & 15, q = lane >> 4;
    const int ztile = local >> 2;
    const int usub = (local >> 1) & 1, vh = local & 1;
    const int z0 = ztile * ZT, u0 = usub * 32;
    const int wh = wave / ZG, zh = wave % ZG;
    const int zloc = zh * 16 + ln;           // slab z row / output z (local)
    const int zg = z0 + zloc;                // global z for this lane's column
    const int v0 = vh * 32 + q * 8;          // this lane's v window base

    for (int i = t; i < M1 * N1 * K1; i += NTHREADS) sC[i] = Cg[i];

    // ---- x2 rows for this lane's 8 v (u-invariant), as j-pairs (float2)
    float2 x2p[4][N1];
#pragma unroll
    for (int jj = 0; jj < 4; ++jj)
#pragma unroll
        for (int n = 0; n < N1; ++n)
            x2p[jj][n] = make_float2(
                x2g[((size_t)zg * 64 + v0 + 2 * jj) * N1 + n],
                x2g[((size_t)zg * 64 + v0 + 2 * jj + 1) * N1 + n]);

    f32x4 acc[ROWT][K1];
#pragma unroll
    for (int rt = 0; rt < ROWT; ++rt)
#pragma unroll
        for (int k = 0; k < K1; ++k) acc[rt][k] = (f32x4){0.f, 0.f, 0.f, 0.f};

    __syncthreads();

#pragma unroll 1
    for (int h = 0; h < 2; ++h) {
        if (h) __syncthreads();   // all reads of previous slab retired
        // ---- build bf16 c1 slab for u in [u0+16h, +16): sc1[z][uu*KNP + k*N1+n]
        for (int i = t; i < ZT * 16 * KN; i += NTHREADS) {
            int z   = i / (16 * KN);
            int r   = i - z * (16 * KN);
            int uu2 = r / KN;
            int j   = r - uu2 * KN;
            int k   = j / N1, n = j - k * N1;
            const float* x1r = x1g + ((size_t)(z0 + z) * 64 + u0 + h * 16 + uu2) * M1;
            float s = 0.f;
#pragma unroll
            for (int m = 0; m < M1; ++m) s += x1r[m] * sC[(m * N1 + n) * K1 + k];
            sc1[z * ZSTR + uu2 * KNP + j] = f2bf(s);
        }
        __syncthreads();

        const unsigned short* cb = sc1 + zloc * ZSTR;

        // initial c1 row + A-frags for first u of this half
        s16x8 cr[NB];
#pragma unroll
        for (int b = 0; b < NB; ++b) cr[b] = *(const s16x8*)(cb + b * 8);
        s16x8 afc[ROWT];
        {
            const unsigned short* wsrc = Wbp + (size_t)(u0 + h * 16) * 4096;
#pragma unroll
            for (int rt = 0; rt < ROWT; ++rt)
                afc[rt] = *(const s16x8*)(wsrc + ((wh * ROWT + rt) * 16 + ln) * 64 + v0);
        }

        // ---- barrier-free u-loop (16 u)
#pragma unroll 1
        for (int uu = 0; uu < 16; ++uu) {
            // unpack current c1 row to fp32 (frees cr for the prefetch)
            float c1v[KN];
#pragma unroll
            for (int j = 0; j < KN; ++j)
                c1v[j] = bf2f((unsigned short)cr[j >> 3][j & 7]);

            // prefetch next u's c1 row + A-frags (consumed next iteration)
            s16x8 afn[ROWT];
            if (uu < 15) {
#pragma unroll
                for (int b = 0; b < NB; ++b)
                    cr[b] = *(const s16x8*)(cb + (uu + 1) * KNP + b * 8);
                const unsigned short* wsrc = Wbp + (size_t)(u0 + h * 16 + uu + 1) * 4096;
#pragma unroll
                for (int rt = 0; rt < ROWT; ++rt)
                    afn[rt] = *(const s16x8*)(wsrc + ((wh * ROWT + rt) * 16 + ln) * 64 + v0);
            }

            // k-loop: build B-frag in registers, MFMA
#pragma unroll
            for (int k = 0; k < K1; ++k) {
                float2 s[4];
#pragma unroll
                for (int jj = 0; jj < 4; ++jj) s[jj] = make_float2(0.f, 0.f);
#pragma unroll
                for (int n = 0; n < N1; ++n) {
                    const float c = c1v[k * N1 + n];
#pragma unroll
                    for (int jj = 0; jj < 4; ++jj) {
                        s[jj].x = fmaf(x2p[jj][n].x, c, s[jj].x);
                        s[jj].y = fmaf(x2p[jj][n].y, c, s[jj].y);
                    }
                }
                union { uint4 u4; s16x8 v; } bf;
                bf.u4 = make_uint4(pk2bf(s[0].x, s[0].y), pk2bf(s[1].x, s[1].y),
                                   pk2bf(s[2].x, s[2].y), pk2bf(s[3].x, s[3].y));
#pragma unroll
                for (int rt = 0; rt < ROWT; ++rt)
                    acc[rt][k] = __builtin_amdgcn_mfma_f32_16x16x32_bf16(
                        afc[rt], bf.v, acc[rt][k], 0, 0, 0);
            }
            if (uu < 15) {
#pragma unroll
                for (int rt = 0; rt < ROWT; ++rt) afc[rt] = afn[rt];
            }
        }
    }

    // ---- epilogue: plain stores to per-(path, usub*2+vh) partials
    const int slice = usub * 2 + vh;
    float* opb = partp + ((size_t)(slice * 1024 + zg) * 64) * K1;
#pragma unroll
    for (int rt = 0; rt < ROWT; ++rt) {
        const int wb = (wh * ROWT + rt) * 16 + q * 4;
#pragma unroll
        for (int k = 0; k < K1; ++k)
#pragma unroll
            for (int r = 0; r < 4; ++r)
                opb[(wb + r) * K1 + k] = acc[rt][k][r];
    }
}

__global__ __launch_bounds__(NTHREADS, 3) void tp_main(KArgs a)
{
    __shared__ __align__(16) char smem[SMEM_BYTES];

    const int bid = blockIdx.x;
    // heavy-first: K1=5 paths (128 blocks each, ZT=32), then K1=3, K1=1 (64 each, ZT=64)
    const int starts[12] = {0, 128, 256, 384, 512, 576, 640, 704, 768, 832, 896, 960};
    int idx = 0;
#pragma unroll
    for (int i = 1; i < 12; ++i) idx += (bid >= starts[i]) ? 1 : 0;
    const int local = bid - starts[idx];

    switch (idx) {            //  M1 N1 K1 ROWT KNP
        case 0:  run_path<1,5,5,2,32>(a.x1[0], a.x2[2], a.Wb + (size_t) 2*262144, a.C[2],  a.part[2],  local, smem); break;
        case 1:  run_path<5,5,5,2,32>(a.x1[2], a.x2[2], a.Wb + (size_t)10*262144, a.C[10], a.part[10], local, smem); break;
        case 2:  run_path<3,3,5,2,16>(a.x1[1], a.x2[1], a.Wb + (size_t) 5*262144, a.C[5],  a.part[5],  local, smem); break;
        case 3:  run_path<5,1,5,2, 8>(a.x1[2], a.x2[0], a.Wb + (size_t) 7*262144, a.C[7],  a.part[7],  local, smem); break;
        case 4:  run_path<3,5,3,4,16>(a.x1[1], a.x2[2], a.Wb + (size_t) 6*262144, a.C[6],  a.part[6],  local, smem); break;
        case 5:  run_path<1,3,3,4,16>(a.x1[0], a.x2[1], a.Wb + (size_t) 1*262144, a.C[1],  a.part[1],  local, smem); break;
        case 6:  run_path<5,3,3,4,16>(a.x1[2], a.x2[1], a.Wb + (size_t) 8*262144, a.C[8],  a.part[8],  local, smem); break;
        case 7:  run_path<3,1,3,4, 8>(a.x1[1], a.x2[0], a.Wb + (size_t) 3*262144, a.C[3],  a.part[3],  local, smem); break;
        case 8:  run_path<5,5,1,4, 8>(a.x1[2], a.x2[2], a.Wb + (size_t) 9*262144, a.C[9],  a.part[9],  local, smem); break;
        case 9:  run_path<3,3,1,4, 8>(a.x1[1], a.x2[1], a.Wb + (size_t) 4*262144, a.C[4],  a.part[4],  local, smem); break;
        case 10: run_path<1,1,1,4, 8>(a.x1[0], a.x2[0], a.Wb + (size_t) 0*262144, a.C[0],  a.part[0],  local, smem); break;
        default: break;
    }
}

// ---------------- reduce: sum partials into out[z][w][9], split by l3 ----------------

struct RArgs {
    const float* part[11];
    float*       out;
};

__global__ __launch_bounds__(NTHREADS) void reduce_out(RArgs r)
{
    const int g   = blockIdx.x >> 8;                             // 0:l0 1:l1 2:l2
    const int tid = (blockIdx.x & 255) * NTHREADS + threadIdx.x; // 65536 = z*64+w
    float* op = r.out + (size_t)tid * 9;

    if (g == 0) {            // k slot 0, paths {0,4,9}, K1=1
        const int P[3] = {0, 4, 9};
        float o = 0.f;
#pragma unroll
        for (int pi = 0; pi < 3; ++pi) {
            const float* pp = r.part[P[pi]];
#pragma unroll
            for (int us = 0; us < 4; ++us)
                o += pp[(size_t)(us * 65536) + tid];
        }
        op[0] = o;
    } else if (g == 1) {     // slots 1..3, paths {1,3,6,8}, K1=3
        const int P[4] = {1, 3, 6, 8};
        float o[3] = {0.f, 0.f, 0.f};
#pragma unroll
        for (int pi = 0; pi < 4; ++pi) {
            const float* pp = r.part[P[pi]];
#pragma unroll
            for (int us = 0; us < 4; ++us) {
                const float* row = pp + ((size_t)(us * 65536) + tid) * 3;
#pragma unroll
                for (int k = 0; k < 3; ++k) o[k] += row[k];
            }
        }
#pragma unroll
        for (int k = 0; k < 3; ++k) op[1 + k] = o[k];
    } else {                 // slots 4..8, paths {2,5,7,10}, K1=5
        const int P[4] = {2, 5, 7, 10};
        float o[5] = {0.f, 0.f, 0.f, 0.f, 0.f};
#pragma unroll
        for (int pi = 0; pi < 4; ++pi) {
            const float* pp = r.part[P[pi]];
#pragma unroll
            for (int us = 0; us < 4; ++us) {
                const float* row = pp + ((size_t)(us * 65536) + tid) * 5;
#pragma unroll
                for (int k = 0; k < 5; ++k) o[k] += row[k];
            }
        }
#pragma unroll
        for (int k = 0; k < 5; ++k) op[4 + k] = o[k];
    }
}

// ---------------- launch ----------------

extern "C" void kernel_launch(void* const* d_in, const int* in_sizes, int n_in,
                              void* d_out, int out_size, void* d_ws, size_t ws_size,
                              hipStream_t stream)
{
    static const int cumK1[11] = {0, 1, 4, 9, 12, 13, 18, 21, 26, 29, 30}; // prefix of K1

    unsigned short* Wb = (unsigned short*)d_ws;                       // 5.77 MB
    float* partbase = (float*)((char*)d_ws + (6u << 20));             // 30.7 MB

    KArgs a;
    // dict order: x1_l0, x2_l0, x1_l1, x2_l1, x1_l2, x2_l2, W, C_0..C_10
    a.x1[0] = (const float*)d_in[0];
    a.x2[0] = (const float*)d_in[1];
    a.x1[1] = (const float*)d_in[2];
    a.x2[1] = (const float*)d_in[3];
    a.x1[2] = (const float*)d_in[4];
    a.x2[2] = (const float*)d_in[5];
    a.Wb = Wb;
    RArgs rr;
    for (int p = 0; p < 11; ++p) {
        a.C[p]    = (const float*)d_in[7 + p];
        a.part[p] = partbase + (size_t)cumK1[p] * 262144;   // 4*1024*64 per K1-slot
        rr.part[p] = a.part[p];
    }
    rr.out = (float*)d_out;

    prep_w<<<dim3(720896 / NTHREADS), NTHREADS, 0, stream>>>((const float*)d_in[6], Wb);
    tp_main<<<dim3(960), NTHREADS, 0, stream>>>(a);
    reduce_out<<<dim3(768), NTHREADS, 0, stream>>>(rr);
}